// Round 1
// baseline (309.898 us; speedup 1.0000x reference)
//
#include <hip/hip_runtime.h>
#include <cstdint>
#include <cstddef>

// Problem constants
#define B_    2
#define S_    2048
#define H_    1024
#define NH_   16
#define HD_   64
#define MTOT  4096   // B_*S_

typedef __attribute__((ext_vector_type(8))) __bf16 bf16x8;
typedef __attribute__((ext_vector_type(4))) float  f32x4;

__device__ __forceinline__ short f2bf(float f) {
  union { float f; unsigned u; } v; v.f = f;
  unsigned r = v.u + 0x7fffu + ((v.u >> 16) & 1u);   // RNE
  return (short)(r >> 16);
}

// ---------------------------------------------------------------------------
// Kernel 1: fp32 -> bf16 conversion of x and the four weight matrices.
// Total 8M elements; each thread converts 4 (float4 load, short4 store).
// ---------------------------------------------------------------------------
__global__ __launch_bounds__(256) void convert_kernel(
    const float* __restrict__ x,  const float* __restrict__ wq,
    const float* __restrict__ wk, const float* __restrict__ wv,
    const float* __restrict__ wd,
    short* __restrict__ xb,  short* __restrict__ wqb, short* __restrict__ wkb,
    short* __restrict__ wvb, short* __restrict__ wdb) {
  size_t i = ((size_t)blockIdx.x * 256 + threadIdx.x) * 4;
  const float* src; short* dst; size_t off;
  if      (i < 4194304u) { src = x;  dst = xb;  off = i; }
  else if (i < 5242880u) { src = wq; dst = wqb; off = i - 4194304u; }
  else if (i < 6291456u) { src = wk; dst = wkb; off = i - 5242880u; }
  else if (i < 7340032u) { src = wv; dst = wvb; off = i - 6291456u; }
  else                   { src = wd; dst = wdb; off = i - 7340032u; }
  float4 v = *(const float4*)(src + off);
  short4 o; o.x = f2bf(v.x); o.y = f2bf(v.y); o.z = f2bf(v.z); o.w = f2bf(v.w);
  *(short4*)(dst + off) = o;
}

// ---------------------------------------------------------------------------
// Kernel 2/4: C[M,N] = A[M,K] * B[N,K]^T + bias,   A,B bf16, K=1024.
// 128x128 tile, 4 waves (2x2), each wave 64x64 = 4x4 frags of 16x16x32 MFMA.
// LDS padded to 72 shorts/row (conflict-free ds_read_b128 frag loads).
// MODE 0: QKV (blockIdx.z selects W/bias/out), epilogue scatters bf16 to
//         [B,NH,S,HD].  MODE 1: fp32 row-major store of y = ctx@Wd^T + bd.
// ---------------------------------------------------------------------------
template<int MODE>
__global__ __launch_bounds__(256) void gemm_bt(
    const short* __restrict__ A,
    const short* __restrict__ Bq, const short* __restrict__ Bk,
    const short* __restrict__ Bv,
    const float* __restrict__ biasq, const float* __restrict__ biask,
    const float* __restrict__ biasv,
    short* __restrict__ outq, short* __restrict__ outk, short* __restrict__ outv,
    float* __restrict__ outy) {
  __shared__ short As[128 * 72];
  __shared__ short Bs[128 * 72];

  const short* Bw; const float* bias; short* outs = nullptr;
  if (MODE == 0) {
    int z = blockIdx.z;
    Bw   = (z == 0) ? Bq    : ((z == 1) ? Bk    : Bv);
    bias = (z == 0) ? biasq : ((z == 1) ? biask : biasv);
    outs = (z == 0) ? outq  : ((z == 1) ? outk  : outv);
  } else {
    Bw = Bq; bias = biasq;
  }

  const int K = 1024;
  int tid  = threadIdx.x;
  int lane = tid & 63, w = tid >> 6;
  int wr = w >> 1, wc = w & 1;
  int m0 = blockIdx.y * 128, n0 = blockIdx.x * 128;
  int l15 = lane & 15, lg = lane >> 4;

  f32x4 acc[4][4];
  for (int m = 0; m < 4; m++)
    for (int n = 0; n < 4; n++) acc[m][n] = {0.f, 0.f, 0.f, 0.f};

  int srow = tid >> 3;           // 0..31
  int scol = (tid & 7) * 8;      // 0,8,..,56

  for (int kt = 0; kt < 16; kt++) {
    int k0 = kt * 64;
    __syncthreads();             // protect LDS from previous iter's readers
    for (int it = 0; it < 4; it++) {
      int r = it * 32 + srow;
      *(int4*)&As[r * 72 + scol] = *(const int4*)&A [(size_t)(m0 + r) * K + k0 + scol];
      *(int4*)&Bs[r * 72 + scol] = *(const int4*)&Bw[(size_t)(n0 + r) * K + k0 + scol];
    }
    __syncthreads();
    for (int kk = 0; kk < 64; kk += 32) {
      int ko = kk + lg * 8;
      bf16x8 af[4], bf[4];
      for (int m = 0; m < 4; m++)
        af[m] = *(const bf16x8*)&As[(wr * 64 + m * 16 + l15) * 72 + ko];
      for (int n = 0; n < 4; n++)
        bf[n] = *(const bf16x8*)&Bs[(wc * 64 + n * 16 + l15) * 72 + ko];
      for (int m = 0; m < 4; m++)
        for (int n = 0; n < 4; n++)
          acc[m][n] = __builtin_amdgcn_mfma_f32_16x16x32_bf16(af[m], bf[n], acc[m][n], 0, 0, 0);
    }
  }

  // epilogue: C row = m0+wr*64+m*16+lg*4+j ; col = n0+wc*64+n*16+l15
  for (int n = 0; n < 4; n++) {
    int col = n0 + wc * 64 + n * 16 + l15;
    float bval = bias[col];
    if (MODE == 0) {
      int h = col >> 6, d = col & 63;
      for (int m = 0; m < 4; m++) {
        int rowb = m0 + wr * 64 + m * 16 + lg * 4;
        for (int j = 0; j < 4; j++) {
          int row = rowb + j;
          int bb = row >> 11, s = row & 2047;
          outs[(((size_t)bb * NH_ + h) * S_ + s) * HD_ + d] = f2bf(acc[m][n][j] + bval);
        }
      }
    } else {
      for (int m = 0; m < 4; m++) {
        int rowb = m0 + wr * 64 + m * 16 + lg * 4;
        for (int j = 0; j < 4; j++)
          outy[(size_t)(rowb + j) * 1024 + col] = acc[m][n][j] + bval;
      }
    }
  }
}

// ---------------------------------------------------------------------------
// Kernel 3: flash attention.  Grid (S/128, B*NH).  4 waves, QTILE=128 (32
// q-rows/wave), KVTILE=64.  Online softmax in fp32; P staged through LDS as
// bf16; V staged transposed for contiguous B-frag reads.  scale = 1/8.
// ---------------------------------------------------------------------------
__global__ __launch_bounds__(256) void attn_kernel(
    const short* __restrict__ Q, const short* __restrict__ K,
    const short* __restrict__ V, const float* __restrict__ mask,
    short* __restrict__ ctx) {
  __shared__ short Qs[128 * 72];
  __shared__ short Ks[64 * 72];
  __shared__ short Vt[64 * 72];   // [d][kv]
  __shared__ short Ps[128 * 72];
  __shared__ float msk[64];

  int bh = blockIdx.y;
  int bidx = bh >> 4, h = bh & 15;
  int q0 = blockIdx.x * 128;
  int tid = threadIdx.x, lane = tid & 63, w = tid >> 6;
  int l15 = lane & 15, lg = lane >> 4;

  const short* Qg = Q + (size_t)bh * S_ * HD_;
  const short* Kg = K + (size_t)bh * S_ * HD_;
  const short* Vg = V + (size_t)bh * S_ * HD_;

  int srow = tid >> 3, scol = (tid & 7) * 8;

  // stage Q once (128x64)
  for (int it = 0; it < 4; it++) {
    int r = it * 32 + srow;
    *(int4*)&Qs[r * 72 + scol] = *(const int4*)&Qg[(size_t)(q0 + r) * HD_ + scol];
  }

  float mrun[2][4], lrun[2][4];
  f32x4 oacc[2][4];
  for (int m = 0; m < 2; m++)
    for (int j = 0; j < 4; j++) { mrun[m][j] = -1e30f; lrun[m][j] = 0.f; }
  for (int m = 0; m < 2; m++)
    for (int n = 0; n < 4; n++) oacc[m][n] = {0.f, 0.f, 0.f, 0.f};

  for (int kt = 0; kt < 32; kt++) {
    __syncthreads();   // previous iter's PV reads done before overwrite
    for (int it = 0; it < 2; it++) {
      int r = it * 32 + srow;
      *(int4*)&Ks[r * 72 + scol] = *(const int4*)&Kg[(size_t)(kt * 64 + r) * HD_ + scol];
      int4 vv = *(const int4*)&Vg[(size_t)(kt * 64 + r) * HD_ + scol];
      short vs[8]; *(int4*)vs = vv;
      for (int j = 0; j < 8; j++) Vt[(scol + j) * 72 + r] = vs[j];  // transpose
    }
    if (tid < 64) msk[tid] = (1.0f - mask[bidx * S_ + kt * 64 + tid]) * -10000.0f;
    __syncthreads();

    // S = (Q K^T) / 8 + mask
    f32x4 s[2][4];
    for (int m = 0; m < 2; m++)
      for (int n = 0; n < 4; n++) s[m][n] = {0.f, 0.f, 0.f, 0.f};
    for (int kk = 0; kk < 64; kk += 32) {
      int ko = kk + lg * 8;
      bf16x8 qa[2], kb[4];
      for (int m = 0; m < 2; m++)
        qa[m] = *(const bf16x8*)&Qs[(w * 32 + m * 16 + l15) * 72 + ko];
      for (int n = 0; n < 4; n++)
        kb[n] = *(const bf16x8*)&Ks[(n * 16 + l15) * 72 + ko];
      for (int m = 0; m < 2; m++)
        for (int n = 0; n < 4; n++)
          s[m][n] = __builtin_amdgcn_mfma_f32_16x16x32_bf16(qa[m], kb[n], s[m][n], 0, 0, 0);
    }
    float mloc[4];
    for (int n = 0; n < 4; n++) mloc[n] = msk[n * 16 + l15];

    float rmax[2][4], rsum[2][4];
    for (int m = 0; m < 2; m++)
      for (int j = 0; j < 4; j++) rmax[m][j] = -1e30f;
    for (int m = 0; m < 2; m++)
      for (int n = 0; n < 4; n++)
        for (int j = 0; j < 4; j++) {
          float t = s[m][n][j] * 0.125f + mloc[n];
          s[m][n][j] = t;
          rmax[m][j] = fmaxf(rmax[m][j], t);
        }
    for (int m = 0; m < 2; m++)
      for (int j = 0; j < 4; j++) {
        float t = rmax[m][j];
        for (int off = 1; off < 16; off <<= 1) t = fmaxf(t, __shfl_xor(t, off));
        rmax[m][j] = t;
      }
    float alpha[2][4];
    for (int m = 0; m < 2; m++)
      for (int j = 0; j < 4; j++) {
        float mn = fmaxf(mrun[m][j], rmax[m][j]);
        alpha[m][j] = __expf(mrun[m][j] - mn);
        mrun[m][j] = mn;
        rsum[m][j] = 0.f;
      }
    for (int m = 0; m < 2; m++)
      for (int n = 0; n < 4; n++)
        for (int j = 0; j < 4; j++) {
          float p = __expf(s[m][n][j] - mrun[m][j]);
          s[m][n][j] = p;
          rsum[m][j] += p;
        }
    for (int m = 0; m < 2; m++)
      for (int j = 0; j < 4; j++) {
        float t = rsum[m][j];
        for (int off = 1; off < 16; off <<= 1) t += __shfl_xor(t, off);
        lrun[m][j] = lrun[m][j] * alpha[m][j] + t;
      }
    for (int m = 0; m < 2; m++)
      for (int n = 0; n < 4; n++)
        for (int j = 0; j < 4; j++) oacc[m][n][j] *= alpha[m][j];

    // P -> LDS (bf16); wave-private rows, within-wave RAW handled by compiler
    for (int m = 0; m < 2; m++)
      for (int n = 0; n < 4; n++)
        for (int j = 0; j < 4; j++)
          Ps[(w * 32 + m * 16 + lg * 4 + j) * 72 + n * 16 + l15] = f2bf(s[m][n][j]);

    // O += P V
    for (int kk = 0; kk < 64; kk += 32) {
      int ko = kk + lg * 8;
      bf16x8 pa[2], vb[4];
      for (int m = 0; m < 2; m++)
        pa[m] = *(const bf16x8*)&Ps[(w * 32 + m * 16 + l15) * 72 + ko];
      for (int n = 0; n < 4; n++)
        vb[n] = *(const bf16x8*)&Vt[(n * 16 + l15) * 72 + ko];
      for (int m = 0; m < 2; m++)
        for (int n = 0; n < 4; n++)
          oacc[m][n] = __builtin_amdgcn_mfma_f32_16x16x32_bf16(pa[m], vb[n], oacc[m][n], 0, 0, 0);
    }
  }

  // epilogue: ctx layout [b][s][h*64+d]  (row-major A for the output gemm)
  for (int m = 0; m < 2; m++)
    for (int j = 0; j < 4; j++) {
      int sg = q0 + w * 32 + m * 16 + lg * 4 + j;
      float inv = 1.0f / lrun[m][j];
      for (int n = 0; n < 4; n++) {
        int d = n * 16 + l15;
        ctx[((size_t)(bidx * S_ + sg) * H_) + h * HD_ + d] = f2bf(oacc[m][n][j] * inv);
      }
    }
}

// ---------------------------------------------------------------------------
// Kernel 5: out = LayerNorm(y + x) * g + b, with finite-mask.  One block per
// row (1024 cols, 256 threads x float4), two-pass mean/var in fp32.
// ---------------------------------------------------------------------------
__global__ __launch_bounds__(256) void ln_kernel(
    const float* __restrict__ y, const float* __restrict__ x,
    const float* __restrict__ g, const float* __restrict__ bta,
    float* __restrict__ out) {
  __shared__ float red[4];
  int row = blockIdx.x;
  int tid = threadIdx.x, lane = tid & 63, w = tid >> 6;
  size_t base = (size_t)row * 1024 + tid * 4;
  float4 yv = *(const float4*)(y + base);
  float4 xv = *(const float4*)(x + base);
  float v0 = yv.x + xv.x, v1 = yv.y + xv.y, v2 = yv.z + xv.z, v3 = yv.w + xv.w;

  float ssum = v0 + v1 + v2 + v3;
  for (int off = 1; off < 64; off <<= 1) ssum += __shfl_xor(ssum, off);
  if (lane == 0) red[w] = ssum;
  __syncthreads();
  float mean = (red[0] + red[1] + red[2] + red[3]) * (1.f / 1024.f);
  __syncthreads();

  float d0 = v0 - mean, d1 = v1 - mean, d2 = v2 - mean, d3 = v3 - mean;
  float sq = d0 * d0 + d1 * d1 + d2 * d2 + d3 * d3;
  for (int off = 1; off < 64; off <<= 1) sq += __shfl_xor(sq, off);
  if (lane == 0) red[w] = sq;
  __syncthreads();
  float var = (red[0] + red[1] + red[2] + red[3]) * (1.f / 1024.f);
  float rs = 1.0f / sqrtf(var + 1e-12f);

  int c = tid * 4;
  float4 gv = *(const float4*)(g + c);
  float4 bv = *(const float4*)(bta + c);
  float o0 = d0 * rs * gv.x + bv.x;
  float o1 = d1 * rs * gv.y + bv.y;
  float o2 = d2 * rs * gv.z + bv.z;
  float o3 = d3 * rs * gv.w + bv.w;
  float4 ov;
  ov.x = __builtin_isfinite(o0) ? o0 : 0.f;
  ov.y = __builtin_isfinite(o1) ? o1 : 0.f;
  ov.z = __builtin_isfinite(o2) ? o2 : 0.f;
  ov.w = __builtin_isfinite(o3) ? o3 : 0.f;
  *(float4*)(out + base) = ov;
}

// ---------------------------------------------------------------------------
extern "C" void kernel_launch(void* const* d_in, const int* in_sizes, int n_in,
                              void* d_out, int out_size, void* d_ws, size_t ws_size,
                              hipStream_t stream) {
  (void)in_sizes; (void)n_in; (void)out_size; (void)ws_size;
  const float* x    = (const float*)d_in[0];
  const float* mask = (const float*)d_in[1];
  const float* Wq   = (const float*)d_in[2];
  const float* bq   = (const float*)d_in[3];
  const float* Wk   = (const float*)d_in[4];
  const float* bk   = (const float*)d_in[5];
  const float* Wv   = (const float*)d_in[6];
  const float* bv   = (const float*)d_in[7];
  const float* Wd   = (const float*)d_in[8];
  const float* bd   = (const float*)d_in[9];
  const float* ln_g = (const float*)d_in[10];
  const float* ln_b = (const float*)d_in[11];
  float* out = (float*)d_out;

  char* ws = (char*)d_ws;
  short* xb   = (short*)(ws);                       //  8 MB  x bf16
  short* wqb  = (short*)(ws + ( 8ull << 20));       //  2 MB
  short* wkb  = (short*)(ws + (10ull << 20));       //  2 MB
  short* wvb  = (short*)(ws + (12ull << 20));       //  2 MB
  short* wdb  = (short*)(ws + (14ull << 20));       //  2 MB
  short* qb   = (short*)(ws + (16ull << 20));       //  8 MB  [B,NH,S,HD]
  short* kb   = (short*)(ws + (24ull << 20));       //  8 MB
  short* vb   = (short*)(ws + (32ull << 20));       //  8 MB
  short* ctxb = (short*)(ws + (40ull << 20));       //  8 MB  [B,S,H]
  float* y    = (float*)(ws + (48ull << 20));       // 16 MB  fp32
  // total 64 MB workspace

  convert_kernel<<<8192, 256, 0, stream>>>(x, Wq, Wk, Wv, Wd, xb, wqb, wkb, wvb, wdb);
  gemm_bt<0><<<dim3(8, 32, 3), 256, 0, stream>>>(xb, wqb, wkb, wvb, bq, bk, bv,
                                                 qb, kb, vb, nullptr);
  attn_kernel<<<dim3(16, 32), 256, 0, stream>>>(qb, kb, vb, mask, ctxb);
  gemm_bt<1><<<dim3(8, 32, 1), 256, 0, stream>>>(ctxb, wdb, nullptr, nullptr, bd,
                                                 nullptr, nullptr, nullptr, nullptr,
                                                 nullptr, y);
  ln_kernel<<<4096, 256, 0, stream>>>(y, x, ln_g, ln_b, out);
}

// Round 2
// 261.303 us; speedup vs baseline: 1.1860x; 1.1860x over previous
//
#include <hip/hip_runtime.h>
#include <cstdint>
#include <cstddef>

// Problem constants
#define B_    2
#define S_    2048
#define H_    1024
#define NH_   16
#define HD_   64

typedef __attribute__((ext_vector_type(8))) __bf16 bf16x8;
typedef __attribute__((ext_vector_type(4))) __bf16 bf16x4;
typedef __attribute__((ext_vector_type(4))) float  f32x4;

typedef __attribute__((address_space(1))) const unsigned int gcu32_t;
typedef __attribute__((address_space(3))) unsigned int lu32_t;
#define GLOAD16(gp, lp) __builtin_amdgcn_global_load_lds((gcu32_t*)(gp), (lu32_t*)(lp), 16, 0, 0)

#if __has_builtin(__builtin_amdgcn_exp2f)
#define EXP2F(x) __builtin_amdgcn_exp2f(x)
#else
#define EXP2F(x) exp2f(x)
#endif

__device__ __forceinline__ short f2bf(float f) {
  union { float f; unsigned u; } v; v.f = f;
  unsigned r = v.u + 0x7fffu + ((v.u >> 16) & 1u);   // RNE
  return (short)(r >> 16);
}

// ---------------------------------------------------------------------------
// Kernel 1: fp32 -> bf16 conversion of x and the four weight matrices.
// ---------------------------------------------------------------------------
__global__ __launch_bounds__(256) void convert_kernel(
    const float* __restrict__ x,  const float* __restrict__ wq,
    const float* __restrict__ wk, const float* __restrict__ wv,
    const float* __restrict__ wd,
    short* __restrict__ xb,  short* __restrict__ wqb, short* __restrict__ wkb,
    short* __restrict__ wvb, short* __restrict__ wdb) {
  size_t i = ((size_t)blockIdx.x * 256 + threadIdx.x) * 4;
  const float* src; short* dst; size_t off;
  if      (i < 4194304u) { src = x;  dst = xb;  off = i; }
  else if (i < 5242880u) { src = wq; dst = wqb; off = i - 4194304u; }
  else if (i < 6291456u) { src = wk; dst = wkb; off = i - 5242880u; }
  else if (i < 7340032u) { src = wv; dst = wvb; off = i - 6291456u; }
  else                   { src = wd; dst = wdb; off = i - 7340032u; }
  float4 v = *(const float4*)(src + off);
  short4 o; o.x = f2bf(v.x); o.y = f2bf(v.y); o.z = f2bf(v.z); o.w = f2bf(v.w);
  *(short4*)(dst + off) = o;
}

// ---------------------------------------------------------------------------
// Kernel 2/4: C[M,N] = A[M,K]*B[N,K]^T + bias, bf16, K=1024.  128x128 tile,
// 4 waves (2x2), 4x4 frags of 16x16x32 MFMA.
// Staging: global_load_lds width=16 into LINEAR LDS [row][64], with the
// G4 XOR swizzle (col ^= (row&7)*8) applied by permuting each lane's GLOBAL
// source column (rule 21: linear dest + inverse-swz source + swz read).
// Reads: ds_read_b128 with col ^= (l15&7)*8  -> uniform 8 dwords/bank.
// ---------------------------------------------------------------------------
template<int MODE>
__global__ __launch_bounds__(256, 2) void gemm_bt(
    const short* __restrict__ A,
    const short* __restrict__ Bq, const short* __restrict__ Bk,
    const short* __restrict__ Bv,
    const float* __restrict__ biasq, const float* __restrict__ biask,
    const float* __restrict__ biasv,
    short* __restrict__ outq, short* __restrict__ outk, short* __restrict__ outv,
    float* __restrict__ outy) {
  __shared__ short As[128 * 64];
  __shared__ short Bs[128 * 64];

  const short* Bw; const float* bias; short* outs = nullptr;
  if (MODE == 0) {
    int z = blockIdx.z;
    Bw   = (z == 0) ? Bq    : ((z == 1) ? Bk    : Bv);
    bias = (z == 0) ? biasq : ((z == 1) ? biask : biasv);
    outs = (z == 0) ? outq  : ((z == 1) ? outk  : outv);
  } else {
    Bw = Bq; bias = biasq;
  }

  const int K = 1024;
  int tid  = threadIdx.x;
  int lane = tid & 63, w = tid >> 6;
  int wr = w >> 1, wc = w & 1;
  int m0 = blockIdx.y * 128, n0 = blockIdx.x * 128;
  int l15 = lane & 15, lg = lane >> 4;

  // swizzled staging source: lane covers row lr of its 8-row group, col block
  // 8*((lane&7)^lr) so that linear LDS dest holds swizzled content.
  int lr = lane >> 3, lc8 = 8 * ((lane & 7) ^ lr);
  const short* Ag = A  + (size_t)(m0 + w * 8 + lr) * K + lc8;
  const short* Bg = Bw + (size_t)(n0 + w * 8 + lr) * K + lc8;

  int cxor = (l15 & 7) * 8;   // read-side swizzle (row&7 == l15&7 for frag rows)

  f32x4 acc[4][4];
  for (int m = 0; m < 4; m++)
    for (int n = 0; n < 4; n++) acc[m][n] = {0.f, 0.f, 0.f, 0.f};

  for (int kt = 0; kt < 16; kt++) {
    __syncthreads();             // previous readers done
    for (int it = 0; it < 4; it++) {
      GLOAD16(Ag + (size_t)it * 32 * K + kt * 64, &As[(w * 8 + it * 32) * 64]);
      GLOAD16(Bg + (size_t)it * 32 * K + kt * 64, &Bs[(w * 8 + it * 32) * 64]);
    }
    __syncthreads();             // vmcnt drained by barrier; tiles published
#pragma unroll
    for (int kkh = 0; kkh < 2; kkh++) {
      int col = (kkh * 32 + lg * 8) ^ cxor;
      bf16x8 af[4], bfr[4];
#pragma unroll
      for (int m = 0; m < 4; m++)
        af[m] = *(const bf16x8*)&As[(wr * 64 + m * 16 + l15) * 64 + col];
#pragma unroll
      for (int n = 0; n < 4; n++)
        bfr[n] = *(const bf16x8*)&Bs[(wc * 64 + n * 16 + l15) * 64 + col];
#pragma unroll
      for (int m = 0; m < 4; m++)
#pragma unroll
        for (int n = 0; n < 4; n++)
          acc[m][n] = __builtin_amdgcn_mfma_f32_16x16x32_bf16(af[m], bfr[n], acc[m][n], 0, 0, 0);
    }
  }

  // epilogue: C row = m0+wr*64+m*16+lg*4+j ; col = n0+wc*64+n*16+l15
  for (int n = 0; n < 4; n++) {
    int col = n0 + wc * 64 + n * 16 + l15;
    float bval = bias[col];
    if (MODE == 0) {
      int h = col >> 6, d = col & 63;
      for (int m = 0; m < 4; m++) {
        int rowb = m0 + wr * 64 + m * 16 + lg * 4;
        for (int j = 0; j < 4; j++) {
          int row = rowb + j;
          int bb = row >> 11, s = row & 2047;
          outs[(((size_t)bb * NH_ + h) * S_ + s) * HD_ + d] = f2bf(acc[m][n][j] + bval);
        }
      }
    } else {
      for (int m = 0; m < 4; m++) {
        int rowb = m0 + wr * 64 + m * 16 + lg * 4;
        for (int j = 0; j < 4; j++)
          outy[(size_t)(rowb + j) * 1024 + col] = acc[m][n][j] + bval;
      }
    }
  }
}

// ---------------------------------------------------------------------------
// Kernel 3: flash attention, rewritten.
//  - grid: flat 512, decoded so all 16 q-blocks of a head share one XCD
//  - Q staged once via global_load_lds (swizzled), hoisted to registers
//  - K double-buffered via global_load_lds (swizzled source / swizzled read)
//  - V reg-staged into subtiled LDS [kv/4][d/16][4][16], consumed with
//    ds_read_b64_tr_b16 (hardware transpose) -> no scalar transpose writes
//  - Ps row stride 84 shorts: conflict-free b16 writes, floor-optimal b128 reads
//  - single __syncthreads per KV tile (issue-early / write-late staging, T14)
//  - softmax in exp2 domain (0.125*log2e folded into the score scale)
// ---------------------------------------------------------------------------
__global__ __launch_bounds__(256, 2) void attn_kernel(
    const short* __restrict__ Q, const short* __restrict__ K,
    const short* __restrict__ V, const float* __restrict__ mask,
    short* __restrict__ ctx) {
  __shared__ short Qs[128 * 64];
  __shared__ short Ks[2][64 * 64];
  __shared__ short Vs[2][64 * 64];   // subtiled: [kv/4][d/16][4][16]
  __shared__ short Ps[128 * 84];
  __shared__ float msk[2][64];

  int b = blockIdx.x;
  int bh = (b & 7) * 4 + ((b >> 3) >> 4);   // XCD-grouped: head's 16 q-blocks co-resident
  int qb = (b >> 3) & 15;
  int bidx = bh >> 4, h = bh & 15;
  int q0 = qb * 128;
  int tid = threadIdx.x, lane = tid & 63, w = tid >> 6;
  int l15 = lane & 15, lg = lane >> 4;

  const short* Qg = Q + (size_t)bh * S_ * HD_;
  const short* Kg = K + (size_t)bh * S_ * HD_;
  const short* Vg = V + (size_t)bh * S_ * HD_;

  int lr = lane >> 3, lc8 = 8 * ((lane & 7) ^ lr);
  int cxor = (l15 & 7) * 8;
  const float MLOG2E = -10000.0f * 1.442695041f;

  // ---- prologue: stage Q (swizzled), K tile 0, V tile 0, mask 0 ----
  for (int it = 0; it < 4; it++) {
    int r = w * 8 + it * 32;
    GLOAD16(Qg + (size_t)(q0 + r + lr) * HD_ + lc8, &Qs[r * 64]);
  }
  for (int it = 0; it < 2; it++) {
    int r = w * 8 + it * 32;
    GLOAD16(Kg + (size_t)(r + lr) * HD_ + lc8, &Ks[0][r * 64]);
  }
  int vrow = tid >> 3, vcol = (tid & 7) * 8;   // vrow 0..31
  int voff = ((vrow >> 2) * 4 + (vcol >> 4)) * 64 + (vrow & 3) * 16 + (vcol & 15);
  {
    int4 v0 = *(const int4*)&Vg[(size_t)vrow * HD_ + vcol];
    int4 v1 = *(const int4*)&Vg[(size_t)(vrow + 32) * HD_ + vcol];
    *(int4*)&Vs[0][voff] = v0;
    *(int4*)&Vs[0][voff + 2048] = v1;
  }
  if (tid < 64) msk[0][tid] = (1.0f - mask[bidx * S_ + tid]) * MLOG2E;
  __syncthreads();

  // hoist Q fragments to registers (swizzled read)
  bf16x8 qreg[2][2];
#pragma unroll
  for (int kkh = 0; kkh < 2; kkh++)
#pragma unroll
    for (int m = 0; m < 2; m++) {
      int row = w * 32 + m * 16 + l15;
      qreg[kkh][m] = *(const bf16x8*)&Qs[row * 64 + ((kkh * 32 + lg * 8) ^ cxor)];
    }

  float mrun[2][4], lrun[2][4];
  f32x4 oacc[2][4];
#pragma unroll
  for (int m = 0; m < 2; m++)
#pragma unroll
    for (int j = 0; j < 4; j++) { mrun[m][j] = -1e30f; lrun[m][j] = 0.f; }
#pragma unroll
  for (int m = 0; m < 2; m++)
#pragma unroll
    for (int n = 0; n < 4; n++) oacc[m][n] = {0.f, 0.f, 0.f, 0.f};

  unsigned vtrbase = (unsigned)(uintptr_t)&Vs[0][0] + (unsigned)(lg * 1024 + l15 * 8);
  const float SC = 0.1803368977f;   // 0.125 * log2(e)

  for (int kt = 0; kt < 32; kt++) {
    int cur = kt & 1;

    // issue next-tile staging early (completes under this tile's compute)
    int4 vp0, vp1; float mp = 0.f;
    if (kt < 31) {
      const short* Kn = Kg + (size_t)(kt + 1) * 64 * HD_;
      for (int it = 0; it < 2; it++) {
        int r = w * 8 + it * 32;
        GLOAD16(Kn + (size_t)(r + lr) * HD_ + lc8, &Ks[cur ^ 1][r * 64]);
      }
      const short* Vn = Vg + (size_t)(kt + 1) * 64 * HD_;
      vp0 = *(const int4*)&Vn[(size_t)vrow * HD_ + vcol];
      vp1 = *(const int4*)&Vn[(size_t)(vrow + 32) * HD_ + vcol];
      if (tid < 64) mp = (1.0f - mask[bidx * S_ + (kt + 1) * 64 + tid]) * MLOG2E;
    }

    // ---- S = QK^T (scores in exp2 domain) ----
    f32x4 sc[2][4];
#pragma unroll
    for (int m = 0; m < 2; m++)
#pragma unroll
      for (int n = 0; n < 4; n++) sc[m][n] = {0.f, 0.f, 0.f, 0.f};
#pragma unroll
    for (int kkh = 0; kkh < 2; kkh++) {
      int col = (kkh * 32 + lg * 8) ^ cxor;
      bf16x8 kb[4];
#pragma unroll
      for (int n = 0; n < 4; n++)
        kb[n] = *(const bf16x8*)&Ks[cur][(n * 16 + l15) * 64 + col];
#pragma unroll
      for (int m = 0; m < 2; m++)
#pragma unroll
        for (int n = 0; n < 4; n++)
          sc[m][n] = __builtin_amdgcn_mfma_f32_16x16x32_bf16(qreg[kkh][m], kb[n], sc[m][n], 0, 0, 0);
    }

    float mloc[4];
#pragma unroll
    for (int n = 0; n < 4; n++) mloc[n] = msk[cur][n * 16 + l15];

    float rmax[2][4];
#pragma unroll
    for (int m = 0; m < 2; m++)
#pragma unroll
      for (int j = 0; j < 4; j++) rmax[m][j] = -1e30f;
#pragma unroll
    for (int m = 0; m < 2; m++)
#pragma unroll
      for (int n = 0; n < 4; n++)
#pragma unroll
        for (int j = 0; j < 4; j++) {
          float t = sc[m][n][j] * SC + mloc[n];
          sc[m][n][j] = t;
          rmax[m][j] = fmaxf(rmax[m][j], t);
        }
    float alpha[2][4], rsum[2][4];
#pragma unroll
    for (int m = 0; m < 2; m++)
#pragma unroll
      for (int j = 0; j < 4; j++) {
        float t = rmax[m][j];
        for (int off = 1; off < 16; off <<= 1) t = fmaxf(t, __shfl_xor(t, off));
        float mn = fmaxf(mrun[m][j], t);
        alpha[m][j] = EXP2F(mrun[m][j] - mn);
        mrun[m][j] = mn;
        rsum[m][j] = 0.f;
      }
#pragma unroll
    for (int m = 0; m < 2; m++)
#pragma unroll
      for (int n = 0; n < 4; n++)
#pragma unroll
        for (int j = 0; j < 4; j++) {
          float p = EXP2F(sc[m][n][j] - mrun[m][j]);
          sc[m][n][j] = p;
          rsum[m][j] += p;
        }
#pragma unroll
    for (int m = 0; m < 2; m++)
#pragma unroll
      for (int j = 0; j < 4; j++) {
        float t = rsum[m][j];
        for (int off = 1; off < 16; off <<= 1) t += __shfl_xor(t, off);
        lrun[m][j] = lrun[m][j] * alpha[m][j] + t;
      }
#pragma unroll
    for (int m = 0; m < 2; m++)
#pragma unroll
      for (int n = 0; n < 4; n++)
#pragma unroll
        for (int j = 0; j < 4; j++) oacc[m][n][j] *= alpha[m][j];

    // P -> LDS bf16 (stride 84: conflict-free b16 writes)
#pragma unroll
    for (int m = 0; m < 2; m++)
#pragma unroll
      for (int n = 0; n < 4; n++)
#pragma unroll
        for (int j = 0; j < 4; j++)
          Ps[(w * 32 + m * 16 + lg * 4 + j) * 84 + n * 16 + l15] = f2bf(sc[m][n][j]);

    // ---- O += P V  (V via hardware transpose reads) ----
    unsigned vtr = vtrbase + (unsigned)(cur * 8192);
#pragma unroll
    for (int kkh = 0; kkh < 2; kkh++) {
      bf16x4 vlo[4], vhi[4];
#pragma unroll
      for (int n = 0; n < 4; n++) {
        unsigned a = vtr + (unsigned)(kkh * 4096 + n * 128);
        asm volatile("ds_read_b64_tr_b16 %0, %2\n\t"
                     "ds_read_b64_tr_b16 %1, %2 offset:512"
                     : "=v"(vlo[n]), "=v"(vhi[n]) : "v"(a));
      }
      bf16x8 pa[2];
#pragma unroll
      for (int m = 0; m < 2; m++)
        pa[m] = *(const bf16x8*)&Ps[(w * 32 + m * 16 + l15) * 84 + kkh * 32 + lg * 8];
      asm volatile("s_waitcnt lgkmcnt(0)" ::: "memory");
      __builtin_amdgcn_sched_barrier(0);
#pragma unroll
      for (int n = 0; n < 4; n++) {
        bf16x8 vb = __builtin_shufflevector(vlo[n], vhi[n], 0, 1, 2, 3, 4, 5, 6, 7);
#pragma unroll
        for (int m = 0; m < 2; m++)
          oacc[m][n] = __builtin_amdgcn_mfma_f32_16x16x32_bf16(pa[m], vb, oacc[m][n], 0, 0, 0);
      }
    }

    // write-late staging for next tile, then the single barrier
    if (kt < 31) {
      *(int4*)&Vs[cur ^ 1][voff] = vp0;
      *(int4*)&Vs[cur ^ 1][voff + 2048] = vp1;
      if (tid < 64) msk[cur ^ 1][tid] = mp;
    }
    __syncthreads();
  }

  // epilogue: ctx layout [b][s][h*64+d]
#pragma unroll
  for (int m = 0; m < 2; m++)
#pragma unroll
    for (int j = 0; j < 4; j++) {
      int sg = q0 + w * 32 + m * 16 + lg * 4 + j;
      float inv = 1.0f / lrun[m][j];
#pragma unroll
      for (int n = 0; n < 4; n++) {
        int d = n * 16 + l15;
        ctx[((size_t)(bidx * S_ + sg) * H_) + h * HD_ + d] = f2bf(oacc[m][n][j] * inv);
      }
    }
}

// ---------------------------------------------------------------------------
// Kernel 5: out = LayerNorm(y + x) * g + b, finite-masked.
// ---------------------------------------------------------------------------
__global__ __launch_bounds__(256) void ln_kernel(
    const float* __restrict__ y, const float* __restrict__ x,
    const float* __restrict__ g, const float* __restrict__ bta,
    float* __restrict__ out) {
  __shared__ float red[4];
  int row = blockIdx.x;
  int tid = threadIdx.x, lane = tid & 63, w = tid >> 6;
  size_t base = (size_t)row * 1024 + tid * 4;
  float4 yv = *(const float4*)(y + base);
  float4 xv = *(const float4*)(x + base);
  float v0 = yv.x + xv.x, v1 = yv.y + xv.y, v2 = yv.z + xv.z, v3 = yv.w + xv.w;

  float ssum = v0 + v1 + v2 + v3;
  for (int off = 1; off < 64; off <<= 1) ssum += __shfl_xor(ssum, off);
  if (lane == 0) red[w] = ssum;
  __syncthreads();
  float mean = (red[0] + red[1] + red[2] + red[3]) * (1.f / 1024.f);
  __syncthreads();

  float d0 = v0 - mean, d1 = v1 - mean, d2 = v2 - mean, d3 = v3 - mean;
  float sq = d0 * d0 + d1 * d1 + d2 * d2 + d3 * d3;
  for (int off = 1; off < 64; off <<= 1) sq += __shfl_xor(sq, off);
  if (lane == 0) red[w] = sq;
  __syncthreads();
  float var = (red[0] + red[1] + red[2] + red[3]) * (1.f / 1024.f);
  float rs = 1.0f / sqrtf(var + 1e-12f);

  int c = tid * 4;
  float4 gv = *(const float4*)(g + c);
  float4 bv = *(const float4*)(bta + c);
  float o0 = d0 * rs * gv.x + bv.x;
  float o1 = d1 * rs * gv.y + bv.y;
  float o2 = d2 * rs * gv.z + bv.z;
  float o3 = d3 * rs * gv.w + bv.w;
  float4 ov;
  ov.x = __builtin_isfinite(o0) ? o0 : 0.f;
  ov.y = __builtin_isfinite(o1) ? o1 : 0.f;
  ov.z = __builtin_isfinite(o2) ? o2 : 0.f;
  ov.w = __builtin_isfinite(o3) ? o3 : 0.f;
  *(float4*)(out + base) = ov;
}

// ---------------------------------------------------------------------------
extern "C" void kernel_launch(void* const* d_in, const int* in_sizes, int n_in,
                              void* d_out, int out_size, void* d_ws, size_t ws_size,
                              hipStream_t stream) {
  (void)in_sizes; (void)n_in; (void)out_size; (void)ws_size;
  const float* x    = (const float*)d_in[0];
  const float* mask = (const float*)d_in[1];
  const float* Wq   = (const float*)d_in[2];
  const float* bq   = (const float*)d_in[3];
  const float* Wk   = (const float*)d_in[4];
  const float* bk   = (const float*)d_in[5];
  const float* Wv   = (const float*)d_in[6];
  const float* bv   = (const float*)d_in[7];
  const float* Wd   = (const float*)d_in[8];
  const float* bd   = (const float*)d_in[9];
  const float* ln_g = (const float*)d_in[10];
  const float* ln_b = (const float*)d_in[11];
  float* out = (float*)d_out;

  char* ws = (char*)d_ws;
  short* xb   = (short*)(ws);                       //  8 MB  x bf16
  short* wqb  = (short*)(ws + ( 8ull << 20));       //  2 MB
  short* wkb  = (short*)(ws + (10ull << 20));       //  2 MB
  short* wvb  = (short*)(ws + (12ull << 20));       //  2 MB
  short* wdb  = (short*)(ws + (14ull << 20));       //  2 MB
  short* qb   = (short*)(ws + (16ull << 20));       //  8 MB  [B,NH,S,HD]
  short* kb   = (short*)(ws + (24ull << 20));       //  8 MB
  short* vb   = (short*)(ws + (32ull << 20));       //  8 MB
  short* ctxb = (short*)(ws + (40ull << 20));       //  8 MB  [B,S,H]
  float* y    = (float*)(ws + (48ull << 20));       // 16 MB  fp32

  convert_kernel<<<8192, 256, 0, stream>>>(x, Wq, Wk, Wv, Wd, xb, wqb, wkb, wvb, wdb);
  gemm_bt<0><<<dim3(8, 32, 3), 256, 0, stream>>>(xb, wqb, wkb, wvb, bq, bk, bv,
                                                 qb, kb, vb, nullptr);
  attn_kernel<<<512, 256, 0, stream>>>(qb, kb, vb, mask, ctxb);
  gemm_bt<1><<<dim3(8, 32, 1), 256, 0, stream>>>(ctxb, wdb, nullptr, nullptr, bd,
                                                 nullptr, nullptr, nullptr, nullptr,
                                                 nullptr, y);
  ln_kernel<<<4096, 256, 0, stream>>>(y, x, ln_g, ln_b, out);
}

// Round 4
// 222.280 us; speedup vs baseline: 1.3942x; 1.1756x over previous
//
#include <hip/hip_runtime.h>
#include <cstdint>
#include <cstddef>

// Problem constants
#define B_    2
#define S_    2048
#define H_    1024
#define NH_   16
#define HD_   64

typedef __attribute__((ext_vector_type(8))) __bf16 bf16x8;
typedef __attribute__((ext_vector_type(4))) __bf16 bf16x4;
typedef __attribute__((ext_vector_type(4))) float  f32x4;
typedef __attribute__((ext_vector_type(2))) unsigned u32x2;

typedef __attribute__((address_space(1))) const unsigned int gcu32_t;
typedef __attribute__((address_space(3))) unsigned int lu32_t;
#define GLOAD16(gp, lp) __builtin_amdgcn_global_load_lds((gcu32_t*)(gp), (lu32_t*)(lp), 16, 0, 0)

#if __has_builtin(__builtin_amdgcn_exp2f)
#define EXP2F(x) __builtin_amdgcn_exp2f(x)
#else
#define EXP2F(x) exp2f(x)
#endif

#define SC_Q 0.1803368977f   // 0.125 * log2(e), folded into Q at projection

__device__ __forceinline__ short f2bf(float f) {
  union { float f; unsigned u; } v; v.f = f;
  unsigned r = v.u + 0x7fffu + ((v.u >> 16) & 1u);   // RNE
  return (short)(r >> 16);
}

// ---------------------------------------------------------------------------
// Kernel 1: fp32 -> bf16 conversion of x and the four weight matrices.
// ---------------------------------------------------------------------------
__global__ __launch_bounds__(256) void convert_kernel(
    const float* __restrict__ x,  const float* __restrict__ wq,
    const float* __restrict__ wk, const float* __restrict__ wv,
    const float* __restrict__ wd,
    short* __restrict__ xb,  short* __restrict__ wqb, short* __restrict__ wkb,
    short* __restrict__ wvb, short* __restrict__ wdb) {
  size_t i = ((size_t)blockIdx.x * 256 + threadIdx.x) * 4;
  const float* src; short* dst; size_t off;
  if      (i < 4194304u) { src = x;  dst = xb;  off = i; }
  else if (i < 5242880u) { src = wq; dst = wqb; off = i - 4194304u; }
  else if (i < 6291456u) { src = wk; dst = wkb; off = i - 5242880u; }
  else if (i < 7340032u) { src = wv; dst = wvb; off = i - 6291456u; }
  else                   { src = wd; dst = wdb; off = i - 7340032u; }
  float4 v = *(const float4*)(src + off);
  short4 o; o.x = f2bf(v.x); o.y = f2bf(v.y); o.z = f2bf(v.z); o.w = f2bf(v.w);
  *(short4*)(dst + off) = o;
}

// ---------------------------------------------------------------------------
// Kernel 2/4: C[M,N] = A[M,K]*B[N,K]^T + bias, bf16, K=1024.  128x128 tile,
// 4 waves (2x2), 4x4 frags of 16x16x32 MFMA.  global_load_lds width=16 with
// XOR swizzle via pre-swizzled global source (rule 21).
// MODE 0: QKV (z selects); Q output (z==0) is pre-scaled by SC_Q.
// MODE 1: fp32 store y = ctx@Wd^T + bd.
// ---------------------------------------------------------------------------
template<int MODE>
__global__ __launch_bounds__(256, 3) void gemm_bt(
    const short* __restrict__ A,
    const short* __restrict__ Bq, const short* __restrict__ Bk,
    const short* __restrict__ Bv,
    const float* __restrict__ biasq, const float* __restrict__ biask,
    const float* __restrict__ biasv,
    short* __restrict__ outq, short* __restrict__ outk, short* __restrict__ outv,
    float* __restrict__ outy) {
  __shared__ short As[128 * 64];
  __shared__ short Bs[128 * 64];

  const short* Bw; const float* bias; short* outs = nullptr;
  float qscale = 1.0f;
  if (MODE == 0) {
    int z = blockIdx.z;
    Bw   = (z == 0) ? Bq    : ((z == 1) ? Bk    : Bv);
    bias = (z == 0) ? biasq : ((z == 1) ? biask : biasv);
    outs = (z == 0) ? outq  : ((z == 1) ? outk  : outv);
    if (z == 0) qscale = SC_Q;
  } else {
    Bw = Bq; bias = biasq;
  }

  const int K = 1024;
  int tid  = threadIdx.x;
  int lane = tid & 63, w = tid >> 6;
  int wr = w >> 1, wc = w & 1;
  int m0 = blockIdx.y * 128, n0 = blockIdx.x * 128;
  int l15 = lane & 15, lg = lane >> 4;

  int lr = lane >> 3, lc8 = 8 * ((lane & 7) ^ lr);
  const short* Ag = A  + (size_t)(m0 + w * 8 + lr) * K + lc8;
  const short* Bg = Bw + (size_t)(n0 + w * 8 + lr) * K + lc8;

  int cxor = (l15 & 7) * 8;

  f32x4 acc[4][4];
  for (int m = 0; m < 4; m++)
    for (int n = 0; n < 4; n++) acc[m][n] = {0.f, 0.f, 0.f, 0.f};

  for (int kt = 0; kt < 16; kt++) {
    __syncthreads();
    for (int it = 0; it < 4; it++) {
      GLOAD16(Ag + (size_t)it * 32 * K + kt * 64, &As[(w * 8 + it * 32) * 64]);
      GLOAD16(Bg + (size_t)it * 32 * K + kt * 64, &Bs[(w * 8 + it * 32) * 64]);
    }
    __syncthreads();
    __builtin_amdgcn_s_setprio(1);
#pragma unroll
    for (int kkh = 0; kkh < 2; kkh++) {
      int col = (kkh * 32 + lg * 8) ^ cxor;
      bf16x8 af[4], bfr[4];
#pragma unroll
      for (int m = 0; m < 4; m++)
        af[m] = *(const bf16x8*)&As[(wr * 64 + m * 16 + l15) * 64 + col];
#pragma unroll
      for (int n = 0; n < 4; n++)
        bfr[n] = *(const bf16x8*)&Bs[(wc * 64 + n * 16 + l15) * 64 + col];
#pragma unroll
      for (int m = 0; m < 4; m++)
#pragma unroll
        for (int n = 0; n < 4; n++)
          acc[m][n] = __builtin_amdgcn_mfma_f32_16x16x32_bf16(af[m], bfr[n], acc[m][n], 0, 0, 0);
    }
    __builtin_amdgcn_s_setprio(0);
  }

  for (int n = 0; n < 4; n++) {
    int col = n0 + wc * 64 + n * 16 + l15;
    float bval = bias[col];
    if (MODE == 0) {
      int h = col >> 6, d = col & 63;
      for (int m = 0; m < 4; m++) {
        int rowb = m0 + wr * 64 + m * 16 + lg * 4;
        for (int j = 0; j < 4; j++) {
          int row = rowb + j;
          int bb = row >> 11, s = row & 2047;
          outs[(((size_t)bb * NH_ + h) * S_ + s) * HD_ + d] = f2bf((acc[m][n][j] + bval) * qscale);
        }
      }
    } else {
      for (int m = 0; m < 4; m++) {
        int rowb = m0 + wr * 64 + m * 16 + lg * 4;
        for (int j = 0; j < 4; j++)
          outy[(size_t)(rowb + j) * 1024 + col] = acc[m][n][j] + bval;
      }
    }
  }
}

// ---------------------------------------------------------------------------
// Kernel 3: flash attention, swapped-operand softmax (T12).
//  - S^T = mfma(K_frag, Q_frag): lane holds P[q=l15][k = n*16+lg*4+j]
//    -> softmax reductions are 16 in-lane ops + 2 shfl_xor (16,32)
//  - P -> LDS via v_cvt_pk_bf16_f32 + 8 ds_write_b64 (row-major [q][k])
//  - O^T = V^T * P^T: V-frags via ds_read_b64_tr_b16 (A-op), P b128 (B-op);
//    running stats stay per-lane -> rescale is scalar mul
//  - defer-max (T13, THR=8) skips rescale most tiles
//  - Q pre-scaled by SC_Q at projection; softmax in exp2 domain
// ---------------------------------------------------------------------------
__global__ __launch_bounds__(256, 2) void attn_kernel(
    const short* __restrict__ Q, const short* __restrict__ K,
    const short* __restrict__ V, const float* __restrict__ mask,
    short* __restrict__ ctx) {
  __shared__ short QPs[128 * 72];       // Q staging (prologue) then Ps [q][72]
  __shared__ short Ks[2][64 * 64];
  __shared__ short Vs[2][64 * 64];      // subtiled: [kv/4][d/16][4][16]
  __shared__ float msk[2][64];

  int b = blockIdx.x;
  int bh = (b & 7) * 4 + ((b >> 3) >> 4);   // XCD-grouped
  int qb = (b >> 3) & 15;
  int bidx = bh >> 4, h = bh & 15;
  int q0 = qb * 128;
  int tid = threadIdx.x, lane = tid & 63, w = tid >> 6;
  int l15 = lane & 15, lg = lane >> 4;

  const short* Qg = Q + (size_t)bh * S_ * HD_;
  const short* Kg = K + (size_t)bh * S_ * HD_;
  const short* Vg = V + (size_t)bh * S_ * HD_;

  int lr = lane >> 3, lc8 = 8 * ((lane & 7) ^ lr);
  int cxor = (l15 & 7) * 8;
  const float MLOG2E = -10000.0f * 1.442695041f;

  // ---- prologue ----
  for (int it = 0; it < 4; it++) {
    int r = w * 8 + it * 32;
    GLOAD16(Qg + (size_t)(q0 + r + lr) * HD_ + lc8, &QPs[r * 64]);
  }
  for (int it = 0; it < 2; it++) {
    int r = w * 8 + it * 32;
    GLOAD16(Kg + (size_t)(r + lr) * HD_ + lc8, &Ks[0][r * 64]);
  }
  int vrow = tid >> 3, vcol = (tid & 7) * 8;
  int voff = ((vrow >> 2) * 4 + (vcol >> 4)) * 64 + (vrow & 3) * 16 + (vcol & 15);
  {
    int4 v0 = *(const int4*)&Vg[(size_t)vrow * HD_ + vcol];
    int4 v1 = *(const int4*)&Vg[(size_t)(vrow + 32) * HD_ + vcol];
    *(int4*)&Vs[0][voff] = v0;
    *(int4*)&Vs[0][voff + 2048] = v1;
  }
  if (tid < 64) msk[0][tid] = (1.0f - mask[bidx * S_ + tid]) * MLOG2E;
  __syncthreads();

  // hoist Q fragments (B-operand: lane holds Q[q = qt*16+l15][k-slice])
  bf16x8 qreg[2][2];
#pragma unroll
  for (int kkh = 0; kkh < 2; kkh++)
#pragma unroll
    for (int qt = 0; qt < 2; qt++) {
      int row = w * 32 + qt * 16 + l15;
      qreg[kkh][qt] = *(const bf16x8*)&QPs[row * 64 + ((kkh * 32 + lg * 8) ^ cxor)];
    }
  __syncthreads();   // all waves done with QPs before it becomes Ps

  float mrun[2] = {-1e30f, -1e30f};
  float lrun[2] = {0.f, 0.f};
  f32x4 oacc[4][2];
#pragma unroll
  for (int dt = 0; dt < 4; dt++)
#pragma unroll
    for (int qt = 0; qt < 2; qt++) oacc[dt][qt] = {0.f, 0.f, 0.f, 0.f};

  unsigned vtrbase = (unsigned)(uintptr_t)&Vs[0][0] + (unsigned)(lg * 1024 + l15 * 8);
  int psrow = (w * 32 + l15) * 72;   // + qt*16*72

  for (int kt = 0; kt < 32; kt++) {
    int cur = kt & 1;

    // issue next-tile staging early
    int4 vp0, vp1; float mp = 0.f;
    if (kt < 31) {
      const short* Kn = Kg + (size_t)(kt + 1) * 64 * HD_;
      for (int it = 0; it < 2; it++) {
        int r = w * 8 + it * 32;
        GLOAD16(Kn + (size_t)(r + lr) * HD_ + lc8, &Ks[cur ^ 1][r * 64]);
      }
      const short* Vn = Vg + (size_t)(kt + 1) * 64 * HD_;
      vp0 = *(const int4*)&Vn[(size_t)vrow * HD_ + vcol];
      vp1 = *(const int4*)&Vn[(size_t)(vrow + 32) * HD_ + vcol];
      if (tid < 64) mp = (1.0f - mask[bidx * S_ + (kt + 1) * 64 + tid]) * MLOG2E;
    }

    // ---- S^T = mfma(K, Q): sc[n][qt], lane q=qt*16+l15, k=n*16+lg*4+j ----
    f32x4 sc[4][2];
#pragma unroll
    for (int n = 0; n < 4; n++)
#pragma unroll
      for (int qt = 0; qt < 2; qt++) sc[n][qt] = {0.f, 0.f, 0.f, 0.f};
    __builtin_amdgcn_s_setprio(1);
#pragma unroll
    for (int kkh = 0; kkh < 2; kkh++) {
      int col = (kkh * 32 + lg * 8) ^ cxor;
      bf16x8 kb[4];
#pragma unroll
      for (int n = 0; n < 4; n++)
        kb[n] = *(const bf16x8*)&Ks[cur][(n * 16 + l15) * 64 + col];
#pragma unroll
      for (int n = 0; n < 4; n++)
#pragma unroll
        for (int qt = 0; qt < 2; qt++)
          sc[n][qt] = __builtin_amdgcn_mfma_f32_16x16x32_bf16(kb[n], qreg[kkh][qt], sc[n][qt], 0, 0, 0);
    }
    __builtin_amdgcn_s_setprio(0);

    // ---- mask add + per-q max (tree in-lane, 2 shfl cross-lane) ----
    f32x4 mv[4];
#pragma unroll
    for (int n = 0; n < 4; n++)
      mv[n] = *(const f32x4*)&msk[cur][n * 16 + lg * 4];
    float rmax[2];
#pragma unroll
    for (int qt = 0; qt < 2; qt++) {
      float pm[4];
#pragma unroll
      for (int n = 0; n < 4; n++) {
        float t0 = sc[n][qt][0] + mv[n][0];
        float t1 = sc[n][qt][1] + mv[n][1];
        float t2 = sc[n][qt][2] + mv[n][2];
        float t3 = sc[n][qt][3] + mv[n][3];
        sc[n][qt][0] = t0; sc[n][qt][1] = t1; sc[n][qt][2] = t2; sc[n][qt][3] = t3;
        pm[n] = fmaxf(fmaxf(t0, t1), fmaxf(t2, t3));
      }
      float t = fmaxf(fmaxf(pm[0], pm[1]), fmaxf(pm[2], pm[3]));
      t = fmaxf(t, __shfl_xor(t, 16));
      t = fmaxf(t, __shfl_xor(t, 32));
      rmax[qt] = t;
    }

    // ---- defer-max rescale (T13) ----
    int need = (rmax[0] > mrun[0] + 8.f) || (rmax[1] > mrun[1] + 8.f);
    if (__any(need)) {
#pragma unroll
      for (int qt = 0; qt < 2; qt++) {
        float mn = fmaxf(mrun[qt], rmax[qt]);
        float a = EXP2F(mrun[qt] - mn);
        lrun[qt] *= a;
        mrun[qt] = mn;
#pragma unroll
        for (int dt = 0; dt < 4; dt++)
#pragma unroll
          for (int j = 0; j < 4; j++) oacc[dt][qt][j] *= a;
      }
    }

    // ---- exp2 + in-lane sum ----
    float rsum[2] = {0.f, 0.f};
#pragma unroll
    for (int n = 0; n < 4; n++)
#pragma unroll
      for (int qt = 0; qt < 2; qt++)
#pragma unroll
        for (int j = 0; j < 4; j++) {
          float p = EXP2F(sc[n][qt][j] - mrun[qt]);
          sc[n][qt][j] = p;
          rsum[qt] += p;
        }

    // ---- pack P to bf16, write [q][k] rows (8 x ds_write_b64) ----
#pragma unroll
    for (int qt = 0; qt < 2; qt++)
#pragma unroll
      for (int n = 0; n < 4; n++) {
        unsigned pk0, pk1;
        asm("v_cvt_pk_bf16_f32 %0, %1, %2" : "=v"(pk0) : "v"(sc[n][qt][0]), "v"(sc[n][qt][1]));
        asm("v_cvt_pk_bf16_f32 %0, %1, %2" : "=v"(pk1) : "v"(sc[n][qt][2]), "v"(sc[n][qt][3]));
        u32x2 wv2; wv2[0] = pk0; wv2[1] = pk1;
        *(u32x2*)&QPs[psrow + qt * 16 * 72 + n * 16 + lg * 4] = wv2;
      }

    // cross-lane sum (off critical path; feeds lrun only)
#pragma unroll
    for (int qt = 0; qt < 2; qt++) {
      float t = rsum[qt];
      t += __shfl_xor(t, 16);
      t += __shfl_xor(t, 32);
      lrun[qt] += t;
    }

    // ---- O^T += V^T P^T ----
    unsigned vtr = vtrbase + (unsigned)(cur * 8192);
#pragma unroll
    for (int kb = 0; kb < 2; kb++) {
      bf16x4 vlo[4], vhi[4];
#pragma unroll
      for (int dt = 0; dt < 4; dt++) {
        unsigned a = vtr + (unsigned)(kb * 4096 + dt * 128);
        asm volatile("ds_read_b64_tr_b16 %0, %2\n\t"
                     "ds_read_b64_tr_b16 %1, %2 offset:512"
                     : "=v"(vlo[dt]), "=v"(vhi[dt]) : "v"(a));
      }
      bf16x8 pb[2];
#pragma unroll
      for (int qt = 0; qt < 2; qt++)
        pb[qt] = *(const bf16x8*)&QPs[psrow + qt * 16 * 72 + kb * 32 + lg * 8];
      asm volatile("s_waitcnt lgkmcnt(0)" ::: "memory");
      __builtin_amdgcn_sched_barrier(0);
      __builtin_amdgcn_s_setprio(1);
#pragma unroll
      for (int dt = 0; dt < 4; dt++) {
        bf16x8 vb = __builtin_shufflevector(vlo[dt], vhi[dt], 0, 1, 2, 3, 4, 5, 6, 7);
#pragma unroll
        for (int qt = 0; qt < 2; qt++)
          oacc[dt][qt] = __builtin_amdgcn_mfma_f32_16x16x32_bf16(vb, pb[qt], oacc[dt][qt], 0, 0, 0);
      }
      __builtin_amdgcn_s_setprio(0);
    }

    // write-late staging for next tile, then the single barrier
    if (kt < 31) {
      *(int4*)&Vs[cur ^ 1][voff] = vp0;
      *(int4*)&Vs[cur ^ 1][voff + 2048] = vp1;
      if (tid < 64) msk[cur ^ 1][tid] = mp;
    }
    __syncthreads();
  }

  // epilogue: lane holds O^T: q = q0+w*32+qt*16+l15, d = dt*16+lg*4+j
#pragma unroll
  for (int qt = 0; qt < 2; qt++) {
    float inv = 1.0f / lrun[qt];
    int sg = q0 + w * 32 + qt * 16 + l15;
    size_t rowbase = ((size_t)(bidx * S_ + sg)) * H_ + h * HD_;
#pragma unroll
    for (int dt = 0; dt < 4; dt++) {
      short4 st;
      st.x = f2bf(oacc[dt][qt][0] * inv);
      st.y = f2bf(oacc[dt][qt][1] * inv);
      st.z = f2bf(oacc[dt][qt][2] * inv);
      st.w = f2bf(oacc[dt][qt][3] * inv);
      *(short4*)&ctx[rowbase + dt * 16 + lg * 4] = st;
    }
  }
}

// ---------------------------------------------------------------------------
// Kernel 5: out = LayerNorm(y + x) * g + b, finite-masked.
// ---------------------------------------------------------------------------
__global__ __launch_bounds__(256) void ln_kernel(
    const float* __restrict__ y, const float* __restrict__ x,
    const float* __restrict__ g, const float* __restrict__ bta,
    float* __restrict__ out) {
  __shared__ float red[4];
  int row = blockIdx.x;
  int tid = threadIdx.x, lane = tid & 63, w = tid >> 6;
  size_t base = (size_t)row * 1024 + tid * 4;
  float4 yv = *(const float4*)(y + base);
  float4 xv = *(const float4*)(x + base);
  float v0 = yv.x + xv.x, v1 = yv.y + xv.y, v2 = yv.z + xv.z, v3 = yv.w + xv.w;

  float ssum = v0 + v1 + v2 + v3;
  for (int off = 1; off < 64; off <<= 1) ssum += __shfl_xor(ssum, off);
  if (lane == 0) red[w] = ssum;
  __syncthreads();
  float mean = (red[0] + red[1] + red[2] + red[3]) * (1.f / 1024.f);
  __syncthreads();

  float d0 = v0 - mean, d1 = v1 - mean, d2 = v2 - mean, d3 = v3 - mean;
  float sq = d0 * d0 + d1 * d1 + d2 * d2 + d3 * d3;
  for (int off = 1; off < 64; off <<= 1) sq += __shfl_xor(sq, off);
  if (lane == 0) red[w] = sq;
  __syncthreads();
  float var = (red[0] + red[1] + red[2] + red[3]) * (1.f / 1024.f);
  float rs = 1.0f / sqrtf(var + 1e-12f);

  int c = tid * 4;
  float4 gv = *(const float4*)(g + c);
  float4 bv = *(const float4*)(bta + c);
  float o0 = d0 * rs * gv.x + bv.x;
  float o1 = d1 * rs * gv.y + bv.y;
  float o2 = d2 * rs * gv.z + bv.z;
  float o3 = d3 * rs * gv.w + bv.w;
  float4 ov;
  ov.x = __builtin_isfinite(o0) ? o0 : 0.f;
  ov.y = __builtin_isfinite(o1) ? o1 : 0.f;
  ov.z = __builtin_isfinite(o2) ? o2 : 0.f;
  ov.w = __builtin_isfinite(o3) ? o3 : 0.f;
  *(float4*)(out + base) = ov;
}

// ---------------------------------------------------------------------------
extern "C" void kernel_launch(void* const* d_in, const int* in_sizes, int n_in,
                              void* d_out, int out_size, void* d_ws, size_t ws_size,
                              hipStream_t stream) {
  (void)in_sizes; (void)n_in; (void)out_size; (void)ws_size;
  const float* x    = (const float*)d_in[0];
  const float* mask = (const float*)d_in[1];
  const float* Wq   = (const float*)d_in[2];
  const float* bq   = (const float*)d_in[3];
  const float* Wk   = (const float*)d_in[4];
  const float* bk   = (const float*)d_in[5];
  const float* Wv   = (const float*)d_in[6];
  const float* bv   = (const float*)d_in[7];
  const float* Wd   = (const float*)d_in[8];
  const float* bd   = (const float*)d_in[9];
  const float* ln_g = (const float*)d_in[10];
  const float* ln_b = (const float*)d_in[11];
  float* out = (float*)d_out;

  char* ws = (char*)d_ws;
  short* xb   = (short*)(ws);                       //  8 MB  x bf16
  short* wqb  = (short*)(ws + ( 8ull << 20));       //  2 MB
  short* wkb  = (short*)(ws + (10ull << 20));       //  2 MB
  short* wvb  = (short*)(ws + (12ull << 20));       //  2 MB
  short* wdb  = (short*)(ws + (14ull << 20));       //  2 MB
  short* qb   = (short*)(ws + (16ull << 20));       //  8 MB  [B,NH,S,HD]
  short* kb   = (short*)(ws + (24ull << 20));       //  8 MB
  short* vb   = (short*)(ws + (32ull << 20));       //  8 MB
  short* ctxb = (short*)(ws + (40ull << 20));       //  8 MB  [B,S,H]
  float* y    = (float*)(ws + (48ull << 20));       // 16 MB  fp32

  convert_kernel<<<8192, 256, 0, stream>>>(x, Wq, Wk, Wv, Wd, xb, wqb, wkb, wvb, wdb);
  gemm_bt<0><<<dim3(8, 32, 3), 256, 0, stream>>>(xb, wqb, wkb, wvb, bq, bk, bv,
                                                 qb, kb, vb, nullptr);
  attn_kernel<<<512, 256, 0, stream>>>(qb, kb, vb, mask, ctxb);
  gemm_bt<1><<<dim3(8, 32, 1), 256, 0, stream>>>(ctxb, wdb, nullptr, nullptr, bd,
                                                 nullptr, nullptr, nullptr, nullptr,
                                                 nullptr, y);
  ln_kernel<<<4096, 256, 0, stream>>>(y, x, ln_g, ln_b, out);
}